// Round 7
// baseline (95.477 us; speedup 1.0000x reference)
//
#include <hip/hip_runtime.h>

#define DIM 128
#define NHEAD 64
#define NROT 8128
#define NSEG 10
#define MHEAD 89088            // sum of n_s^2 floats per head
#define NUNIT 18               // chain (seg,colblock) units per head

typedef float f4 __attribute__((ext_vector_type(4)));

__device__ const int SEG_A[NSEG]   = {0,8,16,24,32,40,48,56,64,80};
__device__ const int SEG_NG[NSEG]  = {1,1,1,1,1,1,1,1,2,6};
__device__ const int SEG_N[NSEG]   = {128,120,112,104,96,88,80,72,64,48};
__device__ const int SEG_OFF[NSEG] = {0,16384,30784,43328,54144,63360,71104,77504,82688,86784};
__device__ const signed char U_SEG[NUNIT] = {0,0,1,1,2,2,3,3,4,4,5,5,6,6,7,7,8,9};
__device__ const signed char U_CB[NUNIT]  = {0,1,0,1,0,1,0,1,0,1,0,1,0,1,0,1,0,0};

// |theta| <= ~0.06: degree-5/4 Taylor, error ~1e-11
__device__ __forceinline__ void sincos_poly(float x, float& sn, float& cn) {
    float x2 = x * x;
    sn = x * fmaf(x2, fmaf(x2, 8.33333333e-3f, -1.66666667e-1f), 1.0f);
    cn = fmaf(x2, fmaf(x2, 4.16666667e-2f, -0.5f), 1.0f);
}

struct Row { f4 q0, q1, q2, q3; };

#define ROTP(c, s, T, v) { float pt = p[T]; p[T] = fmaf((c), pt, (s) * (v)); \
                           (v) = fmaf((c), (v), -((s) * pt)); }

__device__ __forceinline__ void rot8(const Row& r, float p[8], float& v) {
    ROTP(r.q0.x, r.q0.y, 0, v) ROTP(r.q0.z, r.q0.w, 1, v)
    ROTP(r.q1.x, r.q1.y, 2, v) ROTP(r.q1.z, r.q1.w, 3, v)
    ROTP(r.q2.x, r.q2.y, 4, v) ROTP(r.q2.z, r.q2.w, 5, v)
    ROTP(r.q3.x, r.q3.y, 6, v) ROTP(r.q3.z, r.q3.w, 7, v)
}

// XOR-swizzled Q access: row-major [128][64], col ^= (row&31).
// Row access (row fixed): bijective col perm -> 2-way bank alias, free.
// Transposed access (col fixed, row=lane): bank = (cc ^ (row&31)) % 32 covers
// all banks -> 2-way, free. Replaces the +1 pad; saves 1.3 KB -> 4 blocks/CU.
#define QA(r, c) Q[(r)][ (c) ^ ((r) & 31) ]

// ---- Phase 1: per-segment chain; stores M^T (non-mono) for compose ----
__global__ __launch_bounds__(64, 1)
void chain_seg(const float* __restrict__ th_all, float* __restrict__ dst, int mono)
{
    __shared__ float Q[DIM][64];                 // 32 KB (swizzled via QA)
    __shared__ __align__(16) float csx[56 + 8 * 120 * 2];   // 7.9 KB

    const int lane = threadIdx.x;
    const int head = blockIdx.x & 63;
    const int unit = blockIdx.x >> 6;

    int s, cb, ng, n;
    if (mono) { s = 0; cb = unit; ng = 16; n = 128; }
    else      { s = U_SEG[unit]; cb = U_CB[unit]; ng = SEG_NG[s]; n = SEG_N[s]; }
    const int P = mono ? 0 : SEG_A[s];
    const int col_local = cb * 64 + lane;
    const int col_glob  = P + col_local;
    const float* __restrict__ th = th_all + head * NROT;

    for (int r = P; r < DIM; ++r)
        QA(r, lane) = (r == col_glob) ? 1.0f : 0.0f;

    #pragma unroll 1
    for (int g = 0; g < ng; ++g) {
        const int a0  = P + 8 * g;
        const int ntr = 120 - a0;
        const int ne  = 8 * ntr;

        __syncthreads();
        float thx[15];
        #pragma unroll
        for (int it = 0; it < 15; ++it) {
            if (it * 64 < ne) {
                int e = lane + it * 64;
                int t = e & 7, jrel = e >> 3;
                int i = a0 + t;
                thx[it] = th[((i * (255 - i)) >> 1) + jrel + 7 - t];
            }
        }
        float thi = 0.0f;
        if (lane < 28) {
            int t1 = 0, rem = lane;
            while (rem >= 7 - t1) { rem -= 7 - t1; ++t1; }
            int t2 = t1 + 1 + rem;
            int i  = a0 + t1;
            thi = th[((i * (255 - i)) >> 1) + (t2 - t1 - 1)];
        }
        #pragma unroll
        for (int it = 0; it < 15; ++it) {
            if (it * 64 < ne) {
                int e = lane + it * 64;
                float sn, cn; sincos_poly(thx[it], sn, cn);
                csx[56 + 2 * e] = cn; csx[56 + 2 * e + 1] = sn;
            }
        }
        if (lane < 28) {
            float sn, cn; sincos_poly(thi, sn, cn);
            csx[2 * lane] = cn; csx[2 * lane + 1] = sn;
        }
        __syncthreads();

        float p[8];
        #pragma unroll
        for (int t = 0; t < 8; ++t) p[t] = QA(a0 + t, lane);

        {
            int idx = 0;
            #pragma unroll
            for (int t1 = 0; t1 < 8; ++t1) {
                #pragma unroll
                for (int t2 = t1 + 1; t2 < 8; ++t2) {
                    float c = csx[2 * idx], sn = csx[2 * idx + 1];
                    float pa = p[t1];
                    p[t1] = fmaf(c, pa,    sn * p[t2]);
                    p[t2] = fmaf(c, p[t2], -(sn * pa));
                    ++idx;
                }
            }
        }

        if (ntr > 0) {
            const float* cs = csx + 56;
            const int base = a0 + 8;
            Row A0, A1, B0, B1;
            float vA0, vA1, vB0, vB1;
            auto ldrow = [&](Row& R, float& v, int r) {
                const f4* c4 = (const f4*)(cs + 16 * r);
                R.q0 = c4[0]; R.q1 = c4[1]; R.q2 = c4[2]; R.q3 = c4[3];
                v = QA(base + r, lane);
            };
            ldrow(A0, vA0, 0); ldrow(A1, vA1, 1);
            #pragma unroll 1
            for (int r = 0; r < ntr; r += 4) {
                ldrow(B0, vB0, r + 2); ldrow(B1, vB1, r + 3);
                rot8(A0, p, vA0); rot8(A1, p, vA1);
                QA(base + r, lane)     = vA0;
                QA(base + r + 1, lane) = vA1;
                if (r + 4 < ntr) { ldrow(A0, vA0, r + 4); ldrow(A1, vA1, r + 5); }
                rot8(B0, p, vB0); rot8(B1, p, vB1);
                QA(base + r + 2, lane) = vB0;
                QA(base + r + 3, lane) = vB1;
            }
        }

        #pragma unroll
        for (int t = 0; t < 8; ++t) QA(a0 + t, lane) = p[t];
    }

    __syncthreads();     // M^T store reads other lanes' columns

    if (mono) {
        float* o = dst + head * (DIM * DIM) + col_glob;
        #pragma unroll 1
        for (int r = 0; r < DIM; ++r) o[r * DIM] = QA(r, lane);
    } else {
        // store M^T: MT[c][r] = Q[P+r][c], coalesced over r, swizzle-conflict-free
        const int ncol = (n - cb * 64) < 64 ? (n - cb * 64) : 64;
        float* o = dst + (size_t)head * MHEAD + SEG_OFF[s];
        #pragma unroll 1
        for (int cc = 0; cc < ncol; ++cc) {
            const int cg = cb * 64 + cc;
            if (lane < n)      o[cg * n + lane]      = QA(P + lane, cc);
            if (lane + 64 < n) o[cg * n + lane + 64] = QA(P + lane + 64, cc);
        }
    }
}

// ---- Phase 2: compose; A in LDS, M streamed from global (L2) into registers ----
__device__ __forceinline__ void fma4(f4& acc, float m, const f4& a) {
    acc.x = fmaf(m, a.x, acc.x); acc.y = fmaf(m, a.y, acc.y);
    acc.z = fmaf(m, a.z, acc.z); acc.w = fmaf(m, a.w, acc.w);
}

__global__ __launch_bounds__(256, 1)
void compose(const float* __restrict__ M, float* __restrict__ out)
{
    __shared__ float A_sh[DIM][36];          // 18.4 KB, f4-aligned rows

    const int tid  = threadIdx.x;
    const int head = blockIdx.x & 63;        // all 4 quarters of a head -> same XCD
    const int cq   = blockIdx.x >> 6;
    const int c0   = cq * 32;
    const float* __restrict__ Mh = M + (size_t)head * MHEAD;

    // A init = M0 slice (M0^T[c][r] at c*128+r) — coalesced in r
    for (int idx = tid; idx < 32 * DIM; idx += 256) {
        int c = idx >> 7, r = idx & 127;
        A_sh[r][c] = Mh[(c0 + c) * DIM + r];
    }

    const int tx = tid & 7;                  // col group: local cols 4*tx..+4
    const int ty = tid >> 3;                 // row group: rows 4*ty..+4
    const int rb = ty * 4;
    const int cl = tx * 4;

    __syncthreads();

    #pragma unroll 1
    for (int s = 1; s < NSEG; ++s) {
        const int P = SEG_A[s], n = SEG_N[s];
        const bool act = rb < n;
        const int rbs = act ? rb : 0;        // clamp: no OOB reads past ws end
        const float* __restrict__ Ms = Mh + SEG_OFF[s];

        // M^T[k][r]: per wave, 8 distinct f4 at fixed k = one 128B L2 transaction
        f4 acc0 = {0,0,0,0}, acc1 = {0,0,0,0}, acc2 = {0,0,0,0}, acc3 = {0,0,0,0};
        f4 mbuf[8];
        #pragma unroll
        for (int kk = 0; kk < 8; ++kk)
            mbuf[kk] = *(const f4*)&Ms[(size_t)kk * n + rbs];

        #pragma unroll 1
        for (int k0 = 0; k0 < n; k0 += 8) {
            f4 mnext[8];
            const bool have = (k0 + 8) < n;
            if (have) {
                #pragma unroll
                for (int kk = 0; kk < 8; ++kk)
                    mnext[kk] = *(const f4*)&Ms[(size_t)(k0 + 8 + kk) * n + rbs];
            }
            #pragma unroll
            for (int kk = 0; kk < 8; ++kk) {
                const f4 a4 = *(const f4*)&A_sh[P + k0 + kk][cl];
                fma4(acc0, mbuf[kk].x, a4);
                fma4(acc1, mbuf[kk].y, a4);
                fma4(acc2, mbuf[kk].z, a4);
                fma4(acc3, mbuf[kk].w, a4);
            }
            if (have) {
                #pragma unroll
                for (int kk = 0; kk < 8; ++kk) mbuf[kk] = mnext[kk];
            }
        }

        __syncthreads();                      // all reads of old A done
        if (act) {
            *(f4*)&A_sh[P + rb + 0][cl] = acc0;
            *(f4*)&A_sh[P + rb + 1][cl] = acc1;
            *(f4*)&A_sh[P + rb + 2][cl] = acc2;
            *(f4*)&A_sh[P + rb + 3][cl] = acc3;
        }
        __syncthreads();                      // new A visible
    }

    // output: f4 stores, coalesced
    float* o = out + (size_t)head * (DIM * DIM) + c0;
    #pragma unroll 1
    for (int idx = tid; idx < DIM * 8; idx += 256) {
        int r = idx >> 3, c4 = (idx & 7) * 4;
        *(f4*)&o[r * DIM + c4] = *(const f4*)&A_sh[r][c4];
    }
}

extern "C" void kernel_launch(void* const* d_in, const int* in_sizes, int n_in,
                              void* d_out, int out_size, void* d_ws, size_t ws_size,
                              hipStream_t stream) {
    const float* thetas = (const float*)d_in[0];
    float* out = (float*)d_out;
    const size_t need = (size_t)NHEAD * MHEAD * sizeof(float);  // 21.7 MB

    if (ws_size >= need) {
        float* Mws = (float*)d_ws;
        chain_seg<<<dim3(NUNIT * NHEAD), dim3(64), 0, stream>>>(thetas, Mws, 0);
        compose<<<dim3(4 * NHEAD), dim3(256), 0, stream>>>(Mws, out);
    } else {
        chain_seg<<<dim3(2 * NHEAD), dim3(64), 0, stream>>>(thetas, out, 1);
    }
}